// Round 10
// baseline (209.196 us; speedup 1.0000x reference)
//
#include <hip/hip_runtime.h>
#include <hip/hip_bf16.h>

typedef __attribute__((ext_vector_type(8))) short bf16x8;
typedef __attribute__((ext_vector_type(4))) float f32x4;
typedef __attribute__((ext_vector_type(8))) unsigned short us8;

#define MFMA(a, b, c) __builtin_amdgcn_mfma_f32_16x16x32_bf16(a, b, c, 0, 0, 0)

__device__ inline unsigned short f2bf(float f) {
  unsigned u = __builtin_bit_cast(unsigned, f);
  u += 0x7FFF + ((u >> 16) & 1);
  return (unsigned short)(u >> 16);
}
__device__ inline float bf2f(unsigned short s) {
  unsigned u = ((unsigned)s) << 16;
  return __builtin_bit_cast(float, u);
}
__device__ inline unsigned pack2(float lo, float hi) {
  return (unsigned)f2bf(lo) | ((unsigned)f2bf(hi) << 16);
}
__device__ inline void gll16(const unsigned short* gsrc, unsigned short* ldst) {
  __builtin_amdgcn_global_load_lds(
      (const __attribute__((address_space(1))) unsigned int*)gsrc,
      (__attribute__((address_space(3))) unsigned int*)ldst, 16, 0, 0);
}

// ---------------------------------------------------------------------------
// phi/g = W{p,g} @ xh + b. Fused W f32->bf16 convert + xh transpose in LDS.
// grid (8, 2, 16): b, i-half(64), n-chunk(64). 256 thr.
__global__ __launch_bounds__(256) void proj_f2(
    const float* __restrict__ xh,            // [8][256][1024] f32
    const float* __restrict__ Wp, const float* __restrict__ bp,
    const float* __restrict__ Wg, const float* __restrict__ bg,
    unsigned short* __restrict__ phi,        // [8][128][1024] bf16
    unsigned short* __restrict__ gg) {
  __shared__ unsigned short Bs[64 * 256];    // [n][c] swizzled, 32KB
  __shared__ unsigned short As[2][64 * 64];  // [P/G][i][c-chunk] swizzled, 8KB ea
  const int b = blockIdx.x, i0 = blockIdx.y * 64, n0 = blockIdx.z * 64;
  const int t = threadIdx.x, lane = t & 63;
  const int wid = t >> 6, wr = wid >> 1, wc = wid & 1;
  // B-stage: transpose-convert xh[256c][64n] -> Bs[n][256c] bf16, full K.
  #pragma unroll
  for (int it = 0; it < 8; ++it) {
    int s = it * 256 + t;
    int nf = (s & 7) | ((s >> 10) << 3);     // n-f4 index 0..15
    int c2 = (s >> 3) & 127;                 // c-pair 0..127
    const float* p = xh + ((size_t)(b * 256 + 2 * c2)) * 1024 + n0 + nf * 4;
    float4 a = *(const float4*)p;
    float4 bq = *(const float4*)(p + 1024);
    const float* ap = (const float*)&a;
    const float* bp2 = (const float*)&bq;
    #pragma unroll
    for (int i = 0; i < 4; ++i) {
      int n = nf * 4 + i;
      int col32 = (((c2 >> 2) ^ (n & 7)) << 2) | (c2 & 3);  // 0..127
      ((unsigned*)Bs)[n * 128 + col32] = pack2(ap[i], bp2[i]);
    }
  }
  f32x4 accP[2][2] = {};
  f32x4 accG[2][2] = {};
  const int ar = t >> 2, acb = (t & 3) * 16;  // A-stage: row, c-base
  for (int kt = 0; kt < 4; ++kt) {
    // A-stage: convert W[i0+r][kt*64+cb..+16] f32 -> As bf16, swizzled.
    #pragma unroll
    for (int w = 0; w < 2; ++w) {
      const float* W = (w ? Wg : Wp) + (size_t)(i0 + ar) * 256 + kt * 64 + acb;
      #pragma unroll
      for (int q = 0; q < 4; ++q) {
        float4 v = *(const float4*)(W + q * 4);
        int cl0 = acb + q * 4;               // c-local, even
        int c2a = cl0 >> 1, c2b = c2a + 1;   // u32 cols 0..31
        int sa = (((c2a >> 2) ^ (ar & 7)) << 2) | (c2a & 3);
        int sb = (((c2b >> 2) ^ (ar & 7)) << 2) | (c2b & 3);
        ((unsigned*)As[w])[ar * 32 + sa] = pack2(v.x, v.y);
        ((unsigned*)As[w])[ar * 32 + sb] = pack2(v.z, v.w);
      }
    }
    __syncthreads();
    #pragma unroll
    for (int ks = 0; ks < 2; ++ks) {
      bf16x8 bfr[2];
      #pragma unroll
      for (int fm = 0; fm < 2; ++fm) {
        int r = wc * 32 + fm * 16 + (lane & 15);
        int gc = kt * 8 + ks * 4 + (lane >> 4);
        bfr[fm] = *(const bf16x8*)&Bs[r * 256 + (gc ^ (r & 7)) * 8];
      }
      #pragma unroll
      for (int fo = 0; fo < 2; ++fo) {
        int r = wr * 32 + fo * 16 + (lane & 15);
        int ga = ks * 4 + (lane >> 4);
        bf16x8 ap = *(const bf16x8*)&As[0][r * 64 + (ga ^ (r & 7)) * 8];
        bf16x8 ag = *(const bf16x8*)&As[1][r * 64 + (ga ^ (r & 7)) * 8];
        accP[fo][0] = MFMA(ap, bfr[0], accP[fo][0]);
        accP[fo][1] = MFMA(ap, bfr[1], accP[fo][1]);
        accG[fo][0] = MFMA(ag, bfr[0], accG[fo][0]);
        accG[fo][1] = MFMA(ag, bfr[1], accG[fo][1]);
      }
    }
    __syncthreads();
  }
  #pragma unroll
  for (int fo = 0; fo < 2; ++fo) {
    #pragma unroll
    for (int q = 0; q < 4; ++q) {
      int i = i0 + wr * 32 + fo * 16 + (lane >> 4) * 4 + q;
      float vp = bp[i], vg = bg[i];
      #pragma unroll
      for (int fm = 0; fm < 2; ++fm) {
        int n = n0 + wc * 32 + fm * 16 + (lane & 15);
        size_t off = ((size_t)((b * 128) + i)) * 1024 + n;
        phi[off] = f2bf(accP[fo][fm][q] + vp);
        gg[off]  = f2bf(accG[fo][fm][q] + vg);
      }
    }
  }
}

// ---------------------------------------------------------------------------
// Mpart[b][kc][i][j] = sum_{n in chunk of 128} phi[i][n] * g[j][n]. grid (8,8).
__global__ __launch_bounds__(256) void mpart_mfma(
    const unsigned short* __restrict__ phi, const unsigned short* __restrict__ gg,
    float* __restrict__ Mpart) {
  __shared__ unsigned short ps[128 * 128];   // 32KB
  __shared__ unsigned short gs[128 * 128];
  const int b = blockIdx.x, kc = blockIdx.y;
  const int t = threadIdx.x, lane = t & 63;
  const int wid = t >> 6, wr = wid >> 1, wc = wid & 1;
  #pragma unroll
  for (int j = 0; j < 8; ++j) {
    int slot = t + j * 256;                  // 128 r x 16 g
    int r = slot >> 4, gq = slot & 15;
    size_t src = ((size_t)(b * 128 + r)) * 1024 + kc * 128 + (gq ^ (r & 7)) * 8;
    gll16(phi + src, ps + slot * 8);
    gll16(gg + src, gs + slot * 8);
  }
  __syncthreads();
  f32x4 acc[4][4] = {};
  #pragma unroll
  for (int ks = 0; ks < 4; ++ks) {
    bf16x8 av[4], bv[4];
    #pragma unroll
    for (int f = 0; f < 4; ++f) {
      int ra = wr * 64 + f * 16 + (lane & 15);
      int rb = wc * 64 + f * 16 + (lane & 15);
      int gc = ks * 4 + (lane >> 4);
      av[f] = *(const bf16x8*)&ps[ra * 128 + (gc ^ (ra & 7)) * 8];
      bv[f] = *(const bf16x8*)&gs[rb * 128 + (gc ^ (rb & 7)) * 8];
    }
    #pragma unroll
    for (int i = 0; i < 4; ++i)
      #pragma unroll
      for (int j2 = 0; j2 < 4; ++j2)
        acc[i][j2] = MFMA(av[i], bv[j2], acc[i][j2]);
  }
  float* mp = Mpart + ((size_t)(b * 8 + kc)) * 128 * 128;
  #pragma unroll
  for (int i = 0; i < 4; ++i)
    #pragma unroll
    for (int q = 0; q < 4; ++q) {
      int ii = wr * 64 + i * 16 + (lane >> 4) * 4 + q;
      #pragma unroll
      for (int j2 = 0; j2 < 4; ++j2) {
        int jj = wc * 64 + j2 * 16 + (lane & 15);
        mp[ii * 128 + jj] = acc[i][j2][q];
      }
    }
}

// ---------------------------------------------------------------------------
// Fused: M = sum(Mpart)/1024; K2 = Wz@M; W2 = K2@Wt (bf16); b2 = K2@bt + bz.
// grid (8, 8): b, o-chunk of 32. 256 thr. LDS 83KB.
__global__ __launch_bounds__(256) void mkw2(
    const float* __restrict__ Mpart, const float* __restrict__ Wz,
    const float* __restrict__ Wt, const float* __restrict__ bt,
    const float* __restrict__ bz,
    unsigned short* __restrict__ W2b, float* __restrict__ b2) {
  __shared__ float Ms[128 * 129];            // 66KB, pad 129 (bank-free reads)
  __shared__ float Ws2[32 * 132];            // 16.9KB: Wz rows, then K2 rows
  const int b = blockIdx.x, o0 = blockIdx.y * 32;
  const int t = threadIdx.x;
  // Phase 0: stage Wz rows [o0, o0+32)
  #pragma unroll
  for (int q = 0; q < 4; ++q) {
    int f = t + q * 256;                     // 1024 f4: 32 rows x 32 f4
    int o = f >> 5, j4 = (f & 31) * 4;
    float4 v = *(const float4*)&Wz[(size_t)(o0 + o) * 128 + j4];
    Ws2[o * 132 + j4 + 0] = v.x; Ws2[o * 132 + j4 + 1] = v.y;
    Ws2[o * 132 + j4 + 2] = v.z; Ws2[o * 132 + j4 + 3] = v.w;
  }
  // Phase 1: Ms = (1/1024) * sum_kc Mpart[b][kc]
  #pragma unroll
  for (int q = 0; q < 16; ++q) {
    int f = t + q * 256;                     // f4 index [0,4096)
    const float4* p = (const float4*)(Mpart + (size_t)b * 8 * 16384) + f;
    float4 s = p[0];
    #pragma unroll
    for (int kc = 1; kc < 8; ++kc) {
      float4 v = p[(size_t)kc * 4096];
      s.x += v.x; s.y += v.y; s.z += v.z; s.w += v.w;
    }
    const float sc = 1.0f / 1024.0f;
    int i = f >> 5, j = (f & 31) * 4;
    Ms[i * 129 + j + 0] = s.x * sc; Ms[i * 129 + j + 1] = s.y * sc;
    Ms[i * 129 + j + 2] = s.z * sc; Ms[i * 129 + j + 3] = s.w * sc;
  }
  __syncthreads();
  // Phase 2: K2[o][i] = sum_j Wz[o][j] * Ms[i][j]; 16 o per thread-half
  const int i = t & 127, oh = t >> 7;
  float k2[16] = {};
  for (int j = 0; j < 128; ++j) {
    float m = Ms[i * 129 + j];
    #pragma unroll
    for (int oo = 0; oo < 16; ++oo)
      k2[oo] += m * Ws2[(oh * 16 + oo) * 132 + j];
  }
  __syncthreads();                           // Wz reads done; reuse as K2s
  #pragma unroll
  for (int oo = 0; oo < 16; ++oo)
    Ws2[(oh * 16 + oo) * 132 + i] = k2[oo];
  __syncthreads();
  // Phase 3: W2[o][c] = sum_i K2[o][i] * Wt[i][c]; c = t
  const int c = t;
  float acc[32] = {};
  for (int i2 = 0; i2 < 128; ++i2) {
    float wt = Wt[(size_t)i2 * 256 + c];
    #pragma unroll
    for (int o = 0; o < 32; ++o)
      acc[o] += wt * Ws2[o * 132 + i2];
  }
  #pragma unroll
  for (int o = 0; o < 32; ++o)
    W2b[((size_t)(b * 256 + o0 + o)) * 256 + c] = f2bf(acc[o]);
  if (t < 32) {
    float s = 0.f;
    for (int i2 = 0; i2 < 128; ++i2) s += Ws2[t * 132 + i2] * bt[i2];
    b2[b * 256 + o0 + t] = s + bz[o0 + t];
  }
}

// ---------------------------------------------------------------------------
// z = W2 @ xl + b2, xl f32 transposed+converted in LDS. grid (8, 128):
// block = 256 o x 32 m, K=256 in 4 steps of 64.
__global__ __launch_bounds__(256) void mk_z_f(
    const float* __restrict__ xl,            // [8][256][4096] f32
    const unsigned short* __restrict__ W2b,  // [8][256][256] bf16
    const float* __restrict__ b2,
    unsigned short* __restrict__ z,          // [8][256][4096] bf16
    float* __restrict__ sums) {
  __shared__ unsigned short As[256 * 64];    // 32KB [o][c-chunk]
  __shared__ unsigned short Bs[32 * 64];     // 4KB  [m][c-chunk], swizzled
  __shared__ float red[8];
  const int b = blockIdx.x, m0 = blockIdx.y * 32;
  const int t = threadIdx.x, lane = t & 63;
  const int w = t >> 6;                      // wave -> o-range w*64
  const int mf = t & 7, c2 = t >> 3;         // B-stage coords
  f32x4 acc[4][2] = {};                      // [o-frag][m-frag]
  for (int kt = 0; kt < 4; ++kt) {
    #pragma unroll
    for (int j = 0; j < 8; ++j) {
      int slot = t + j * 256;                // 256 r x 8 g
      int r = slot >> 3, gq = slot & 7;
      gll16(W2b + ((size_t)(b * 256 + r)) * 256 + kt * 64 + (gq ^ (r & 7)) * 8,
            As + slot * 8);
    }
    // B: transpose-convert xl[kt*64..][m0..m0+32] -> Bs[m][c]
    {
      const float* p = xl + ((size_t)(b * 256 + kt * 64 + 2 * c2)) * 4096 + m0 + mf * 4;
      float4 a = *(const float4*)p;
      float4 bq = *(const float4*)(p + 4096);
      const float* ap = (const float*)&a;
      const float* bp2 = (const float*)&bq;
      #pragma unroll
      for (int i = 0; i < 4; ++i) {
        int m = mf * 4 + i;
        int col32 = (((c2 >> 2) ^ (m & 7)) << 2) | (c2 & 3);  // 0..31
        ((unsigned*)Bs)[m * 32 + col32] = pack2(ap[i], bp2[i]);
      }
    }
    __syncthreads();
    #pragma unroll
    for (int ks = 0; ks < 2; ++ks) {
      bf16x8 av[4], bv[2];
      #pragma unroll
      for (int f = 0; f < 2; ++f) {
        int rb = f * 16 + (lane & 15);
        int gc = ks * 4 + (lane >> 4);
        bv[f] = *(const bf16x8*)&Bs[rb * 64 + (gc ^ (rb & 7)) * 8];
      }
      #pragma unroll
      for (int f = 0; f < 4; ++f) {
        int ra = w * 64 + f * 16 + (lane & 15);
        int gc = ks * 4 + (lane >> 4);
        av[f] = *(const bf16x8*)&As[ra * 64 + (gc ^ (ra & 7)) * 8];
      }
      #pragma unroll
      for (int i = 0; i < 4; ++i)
        #pragma unroll
        for (int j2 = 0; j2 < 2; ++j2)
          acc[i][j2] = MFMA(av[i], bv[j2], acc[i][j2]);
    }
    __syncthreads();
  }
  float ls = 0.f, ls2 = 0.f;
  #pragma unroll
  for (int i = 0; i < 4; ++i) {
    #pragma unroll
    for (int q = 0; q < 4; ++q) {
      int o = w * 64 + i * 16 + (lane >> 4) * 4 + q;
      float bias = b2[b * 256 + o];
      #pragma unroll
      for (int j2 = 0; j2 < 2; ++j2) {
        int m = m0 + j2 * 16 + (lane & 15);
        float v = acc[i][j2][q] + bias;
        z[((size_t)(b * 256 + o)) * 4096 + m] = f2bf(v);
        ls += v; ls2 += v * v;
      }
    }
  }
  #pragma unroll
  for (int off = 32; off > 0; off >>= 1) {
    ls  += __shfl_down(ls, off);
    ls2 += __shfl_down(ls2, off);
  }
  if ((t & 63) == 0) { red[w * 2] = ls; red[w * 2 + 1] = ls2; }
  __syncthreads();
  if (t == 0) {
    atomicAdd(&sums[b * 2 + 0], red[0] + red[2] + red[4] + red[6]);
    atomicAdd(&sums[b * 2 + 1], red[1] + red[3] + red[5] + red[7]);
  }
}

// ---------------------------------------------------------------------------
// GroupNorm(1) + affine. grid 4096.
__global__ __launch_bounds__(256) void ln_out(
    const unsigned short* __restrict__ z, const float* __restrict__ sums,
    const float* __restrict__ gamma, const float* __restrict__ beta,
    float* __restrict__ out) {
  size_t i8 = (size_t)blockIdx.x * 256 + threadIdx.x;
  int b = (int)(i8 >> 17);
  int o = (int)((i8 >> 9) & 255);
  float s = sums[b * 2], s2 = sums[b * 2 + 1];
  const float invN = 1.0f / (256.0f * 4096.0f);
  float mu = s * invN;
  float var = s2 * invN - mu * mu;
  float rs = rsqrtf(var + 1e-5f);
  float ga = gamma[o] * rs;
  float be = beta[o] - mu * rs * gamma[o];
  us8 u = *(const us8*)&z[i8 * 8];
  float4 r0, r1;
  r0.x = bf2f(u[0]) * ga + be; r0.y = bf2f(u[1]) * ga + be;
  r0.z = bf2f(u[2]) * ga + be; r0.w = bf2f(u[3]) * ga + be;
  r1.x = bf2f(u[4]) * ga + be; r1.y = bf2f(u[5]) * ga + be;
  r1.z = bf2f(u[6]) * ga + be; r1.w = bf2f(u[7]) * ga + be;
  *(float4*)&out[i8 * 8] = r0;
  *(float4*)&out[i8 * 8 + 4] = r1;
}

// ---------------------------------------------------------------------------
extern "C" void kernel_launch(void* const* d_in, const int* in_sizes, int n_in,
                              void* d_out, int out_size, void* d_ws, size_t ws_size,
                              hipStream_t stream) {
  const float* xh    = (const float*)d_in[0];
  const float* xl    = (const float*)d_in[1];
  const float* Wg    = (const float*)d_in[2];
  const float* bg    = (const float*)d_in[3];
  const float* Wt    = (const float*)d_in[4];
  const float* bt    = (const float*)d_in[5];
  const float* Wp    = (const float*)d_in[6];
  const float* bp    = (const float*)d_in[7];
  const float* Wz    = (const float*)d_in[8];
  const float* bz    = (const float*)d_in[9];
  const float* gamma = (const float*)d_in[10];
  const float* beta  = (const float*)d_in[11];
  float* out = (float*)d_out;
  float* ws = (float*)d_ws;

  // ws layout (f32 slots). zbuf [0, 4194304) overlaps ONLY dead-by-then
  // buffers (phi, gbuf, Mpart). W2b/b2/sums live PAST zbuf's range —
  // round-9 bug was placing them inside it (mk_z_f z-writes clobbered them).
  unsigned short* phi  = (unsigned short*)(ws + 0);        // [0,       524288)
  unsigned short* gbuf = (unsigned short*)(ws + 524288);   // [524288, 1048576)
  float* Mpart = ws + 1048576;                             // [1048576,2097152)
  unsigned short* zbuf = (unsigned short*)(ws + 0);        // [0,      4194304)
  unsigned short* W2b  = (unsigned short*)(ws + 4194304);  // [4194304,4456448)
  float* b2    = ws + 4456448;                             // 2,048 f32
  float* sums  = ws + 4458496;                             // 16 f32

  hipMemsetAsync(sums, 0, 16 * sizeof(float), stream);

  proj_f2<<<dim3(8, 2, 16), 256, 0, stream>>>(xh, Wp, bp, Wg, bg, phi, gbuf);
  mpart_mfma<<<dim3(8, 8), 256, 0, stream>>>(phi, gbuf, Mpart);
  mkw2<<<dim3(8, 8), 256, 0, stream>>>(Mpart, Wz, Wt, bt, bz, W2b, b2);
  mk_z_f<<<dim3(8, 128), 256, 0, stream>>>(xl, W2b, b2, zbuf, sums);
  ln_out<<<4096, 256, 0, stream>>>(zbuf, sums, gamma, beta, out);
}

// Round 12
// 178.592 us; speedup vs baseline: 1.1714x; 1.1714x over previous
//
#include <hip/hip_runtime.h>
#include <hip/hip_bf16.h>

typedef __attribute__((ext_vector_type(8))) short bf16x8;
typedef __attribute__((ext_vector_type(4))) float f32x4;
typedef __attribute__((ext_vector_type(4))) unsigned short us4;
typedef __attribute__((ext_vector_type(8))) unsigned short us8;

#define MFMA(a, b, c) __builtin_amdgcn_mfma_f32_16x16x32_bf16(a, b, c, 0, 0, 0)

__device__ inline unsigned short f2bf(float f) {
  unsigned u = __builtin_bit_cast(unsigned, f);
  u += 0x7FFF + ((u >> 16) & 1);
  return (unsigned short)(u >> 16);
}
__device__ inline float bf2f(unsigned short s) {
  unsigned u = ((unsigned)s) << 16;
  return __builtin_bit_cast(float, u);
}
__device__ inline unsigned pack2(float lo, float hi) {
  return (unsigned)f2bf(lo) | ((unsigned)f2bf(hi) << 16);
}
__device__ inline void gll16(const unsigned short* gsrc, unsigned short* ldst) {
  __builtin_amdgcn_global_load_lds(
      (const __attribute__((address_space(1))) unsigned int*)gsrc,
      (__attribute__((address_space(3))) unsigned int*)ldst, 16, 0, 0);
}

// ---------------------------------------------------------------------------
// phi/g = W{p,g} @ xh + b. Fused W f32->bf16 convert + xh transpose in LDS.
// grid (8, 2, 16): b, i-half(64), n-chunk(64). 256 thr.
__global__ __launch_bounds__(256) void proj_f2(
    const float* __restrict__ xh,            // [8][256][1024] f32
    const float* __restrict__ Wp, const float* __restrict__ bp,
    const float* __restrict__ Wg, const float* __restrict__ bg,
    unsigned short* __restrict__ phi,        // [8][128][1024] bf16
    unsigned short* __restrict__ gg) {
  __shared__ unsigned short Bs[64 * 256];    // [n][c] swizzled, 32KB
  __shared__ unsigned short As[2][64 * 64];  // [P/G][i][c-chunk] swizzled
  const int b = blockIdx.x, i0 = blockIdx.y * 64, n0 = blockIdx.z * 64;
  const int t = threadIdx.x, lane = t & 63;
  const int wid = t >> 6, wr = wid >> 1, wc = wid & 1;
  #pragma unroll
  for (int it = 0; it < 8; ++it) {
    int s = it * 256 + t;
    int nf = (s & 7) | ((s >> 10) << 3);     // n-f4 index 0..15
    int c2 = (s >> 3) & 127;                 // c-pair 0..127
    const float* p = xh + ((size_t)(b * 256 + 2 * c2)) * 1024 + n0 + nf * 4;
    float4 a = *(const float4*)p;
    float4 bq = *(const float4*)(p + 1024);
    const float* ap = (const float*)&a;
    const float* bp2 = (const float*)&bq;
    #pragma unroll
    for (int i = 0; i < 4; ++i) {
      int n = nf * 4 + i;
      int col32 = (((c2 >> 2) ^ (n & 7)) << 2) | (c2 & 3);  // 0..127
      ((unsigned*)Bs)[n * 128 + col32] = pack2(ap[i], bp2[i]);
    }
  }
  f32x4 accP[2][2] = {};
  f32x4 accG[2][2] = {};
  const int ar = t >> 2, acb = (t & 3) * 16;
  for (int kt = 0; kt < 4; ++kt) {
    #pragma unroll
    for (int w = 0; w < 2; ++w) {
      const float* W = (w ? Wg : Wp) + (size_t)(i0 + ar) * 256 + kt * 64 + acb;
      #pragma unroll
      for (int q = 0; q < 4; ++q) {
        float4 v = *(const float4*)(W + q * 4);
        int cl0 = acb + q * 4;
        int c2a = cl0 >> 1, c2b = c2a + 1;
        int sa = (((c2a >> 2) ^ (ar & 7)) << 2) | (c2a & 3);
        int sb = (((c2b >> 2) ^ (ar & 7)) << 2) | (c2b & 3);
        ((unsigned*)As[w])[ar * 32 + sa] = pack2(v.x, v.y);
        ((unsigned*)As[w])[ar * 32 + sb] = pack2(v.z, v.w);
      }
    }
    __syncthreads();
    #pragma unroll
    for (int ks = 0; ks < 2; ++ks) {
      bf16x8 bfr[2];
      #pragma unroll
      for (int fm = 0; fm < 2; ++fm) {
        int r = wc * 32 + fm * 16 + (lane & 15);
        int gc = kt * 8 + ks * 4 + (lane >> 4);
        bfr[fm] = *(const bf16x8*)&Bs[r * 256 + (gc ^ (r & 7)) * 8];
      }
      #pragma unroll
      for (int fo = 0; fo < 2; ++fo) {
        int r = wr * 32 + fo * 16 + (lane & 15);
        int ga = ks * 4 + (lane >> 4);
        bf16x8 ap = *(const bf16x8*)&As[0][r * 64 + (ga ^ (r & 7)) * 8];
        bf16x8 ag = *(const bf16x8*)&As[1][r * 64 + (ga ^ (r & 7)) * 8];
        accP[fo][0] = MFMA(ap, bfr[0], accP[fo][0]);
        accP[fo][1] = MFMA(ap, bfr[1], accP[fo][1]);
        accG[fo][0] = MFMA(ag, bfr[0], accG[fo][0]);
        accG[fo][1] = MFMA(ag, bfr[1], accG[fo][1]);
      }
    }
    __syncthreads();
  }
  #pragma unroll
  for (int fo = 0; fo < 2; ++fo) {
    #pragma unroll
    for (int q = 0; q < 4; ++q) {
      int i = i0 + wr * 32 + fo * 16 + (lane >> 4) * 4 + q;
      float vp = bp[i], vg = bg[i];
      #pragma unroll
      for (int fm = 0; fm < 2; ++fm) {
        int n = n0 + wc * 32 + fm * 16 + (lane & 15);
        size_t off = ((size_t)((b * 128) + i)) * 1024 + n;
        phi[off] = f2bf(accP[fo][fm][q] + vp);
        gg[off]  = f2bf(accG[fo][fm][q] + vg);
      }
    }
  }
}

// ---------------------------------------------------------------------------
// Mpart[b][kc][i][j] = sum_{n chunk of 128} phi[i][n]*g[j][n]. grid (8,8).
__global__ __launch_bounds__(256) void mpart_mfma(
    const unsigned short* __restrict__ phi, const unsigned short* __restrict__ gg,
    float* __restrict__ Mpart) {
  __shared__ unsigned short ps[128 * 128];
  __shared__ unsigned short gs[128 * 128];
  const int b = blockIdx.x, kc = blockIdx.y;
  const int t = threadIdx.x, lane = t & 63;
  const int wid = t >> 6, wr = wid >> 1, wc = wid & 1;
  #pragma unroll
  for (int j = 0; j < 8; ++j) {
    int slot = t + j * 256;
    int r = slot >> 4, gq = slot & 15;
    size_t src = ((size_t)(b * 128 + r)) * 1024 + kc * 128 + (gq ^ (r & 7)) * 8;
    gll16(phi + src, ps + slot * 8);
    gll16(gg + src, gs + slot * 8);
  }
  __syncthreads();
  f32x4 acc[4][4] = {};
  #pragma unroll
  for (int ks = 0; ks < 4; ++ks) {
    bf16x8 av[4], bv[4];
    #pragma unroll
    for (int f = 0; f < 4; ++f) {
      int ra = wr * 64 + f * 16 + (lane & 15);
      int rb = wc * 64 + f * 16 + (lane & 15);
      int gc = ks * 4 + (lane >> 4);
      av[f] = *(const bf16x8*)&ps[ra * 128 + (gc ^ (ra & 7)) * 8];
      bv[f] = *(const bf16x8*)&gs[rb * 128 + (gc ^ (rb & 7)) * 8];
    }
    #pragma unroll
    for (int i = 0; i < 4; ++i)
      #pragma unroll
      for (int j2 = 0; j2 < 4; ++j2)
        acc[i][j2] = MFMA(av[i], bv[j2], acc[i][j2]);
  }
  float* mp = Mpart + ((size_t)(b * 8 + kc)) * 128 * 128;
  #pragma unroll
  for (int i = 0; i < 4; ++i)
    #pragma unroll
    for (int q = 0; q < 4; ++q) {
      int ii = wr * 64 + i * 16 + (lane >> 4) * 4 + q;
      #pragma unroll
      for (int j2 = 0; j2 < 4; ++j2) {
        int jj = wc * 64 + j2 * 16 + (lane & 15);
        mp[ii * 128 + jj] = acc[i][j2][q];
      }
    }
}

// ---------------------------------------------------------------------------
// M_bf[b][i][j] bf16 = sum_kc Mpart / 1024, granule PRE-SWIZZLED for gll16.
// grid 128, 256 thr.
__global__ __launch_bounds__(256) void mreduce_bf(
    const float* __restrict__ Mpart, unsigned short* __restrict__ M_bf) {
  int f = blockIdx.x * 256 + threadIdx.x;    // f4 index [0, 32768)
  int b = f >> 12, r = f & 4095;             // 4096 f4 per batch (128i x 32 j4)
  const float4* p = (const float4*)Mpart + (size_t)b * 32768 + r;
  float4 s = p[0];
  #pragma unroll
  for (int kc = 1; kc < 8; ++kc) {
    float4 v = p[(size_t)kc * 4096];
    s.x += v.x; s.y += v.y; s.z += v.z; s.w += v.w;
  }
  const float sc = 1.0f / 1024.0f;
  us4 o;
  o[0] = f2bf(s.x * sc); o[1] = f2bf(s.y * sc);
  o[2] = f2bf(s.z * sc); o[3] = f2bf(s.w * sc);
  int i = r >> 5, j4 = r & 31;
  int gsw = (j4 >> 1) ^ (i & 7);             // swizzled granule
  *(us4*)&M_bf[((size_t)(b * 128 + i)) * 128 + gsw * 8 + (j4 & 1) * 4] = o;
}

// ---------------------------------------------------------------------------
// MFMA chain: K2 = Wz@M; W2 = K2@Wt (bf16 out); b2 = K2@bt + bz.
// grid (8, 2): batch, o-half(128). 256 thr, 4 waves (32 o each). LDS 128KB.
__global__ __launch_bounds__(256) void k2w2_mfma(
    const unsigned short* __restrict__ M_bf,  // [8][128][128] bf16 pre-swz
    const float* __restrict__ Wz, const float* __restrict__ Wt,
    const float* __restrict__ bt, const float* __restrict__ bz,
    unsigned short* __restrict__ W2b, float* __restrict__ b2) {
  __shared__ unsigned short Wz_s[128 * 128]; // [o][j] swizzled, 32KB
  __shared__ unsigned short M_s[128 * 128];  // [i][j] swizzled, 32KB
  __shared__ unsigned short K2_s[128 * 128]; // [o][i] swizzled, 32KB
  __shared__ unsigned short Wt_s[128 * 128]; // [c][i] swizzled, 32KB (chunked)
  const int b = blockIdx.x, o0 = blockIdx.y * 128;
  const int t = threadIdx.x, lane = t & 63;
  const int w = t >> 6;
  // Stage Wz rows [o0..o0+128), convert f32->bf16, swizzled.
  #pragma unroll
  for (int it = 0; it < 16; ++it) {
    int f = it * 256 + t;                    // 4096 f4: 128 r x 32 j4
    int r = f >> 5, j4 = f & 31;
    float4 v = *(const float4*)&Wz[(size_t)(o0 + r) * 128 + j4 * 4];
    us4 o;
    o[0] = f2bf(v.x); o[1] = f2bf(v.y); o[2] = f2bf(v.z); o[3] = f2bf(v.w);
    int gsw = (j4 >> 1) ^ (r & 7);
    *(us4*)&Wz_s[r * 128 + gsw * 8 + (j4 & 1) * 4] = o;
  }
  // Stage M via gll16 (source already granule-swizzled).
  #pragma unroll
  for (int j = 0; j < 8; ++j) {
    int slot = t + j * 256;                  // 2048: 128 r x 16 g
    int r = slot >> 4, gq = slot & 15;
    gll16(M_bf + ((size_t)(b * 128 + r)) * 128 + gq * 8, M_s + slot * 8);
  }
  __syncthreads();
  // MFMA1: K2[o][i] = sum_j Wz[o][j] * M[i][j]. per wave: 32 o x 128 i.
  f32x4 acc1[2][8] = {};
  #pragma unroll
  for (int ks = 0; ks < 4; ++ks) {
    int gc = ks * 4 + (lane >> 4);
    bf16x8 av[2], bv[8];
    #pragma unroll
    for (int fo = 0; fo < 2; ++fo) {
      int ro = w * 32 + fo * 16 + (lane & 15);
      av[fo] = *(const bf16x8*)&Wz_s[ro * 128 + (gc ^ (ro & 7)) * 8];
    }
    #pragma unroll
    for (int fi = 0; fi < 8; ++fi) {
      int ri = fi * 16 + (lane & 15);
      bv[fi] = *(const bf16x8*)&M_s[ri * 128 + (gc ^ (ri & 7)) * 8];
    }
    #pragma unroll
    for (int fo = 0; fo < 2; ++fo)
      #pragma unroll
      for (int fi = 0; fi < 8; ++fi)
        acc1[fo][fi] = MFMA(av[fo], bv[fi], acc1[fo][fi]);
  }
  // Write K2 -> LDS bf16, swizzled. C layout: row=(lane>>4)*4+q, col=lane&15.
  #pragma unroll
  for (int fo = 0; fo < 2; ++fo)
    #pragma unroll
    for (int q = 0; q < 4; ++q) {
      int ol = w * 32 + fo * 16 + (lane >> 4) * 4 + q;
      #pragma unroll
      for (int fi = 0; fi < 8; ++fi) {
        int i = fi * 16 + (lane & 15);
        K2_s[ol * 128 + (((i >> 3) ^ (ol & 7)) * 8) + (i & 7)] =
            f2bf(acc1[fo][fi][q]);
      }
    }
  // Stage Wt chunk 0 (c in [0,128)): WtT[c][i] bf16 swizzled.
  #pragma unroll
  for (int it = 0; it < 16; ++it) {
    int f = it * 256 + t;                    // 4096: 128 c x 32 i-quads
    int cl = f & 127, iq = (f >> 7) & 31;
    int i0 = iq * 4;
    us4 o;
    o[0] = f2bf(Wt[(size_t)(i0 + 0) * 256 + cl]);
    o[1] = f2bf(Wt[(size_t)(i0 + 1) * 256 + cl]);
    o[2] = f2bf(Wt[(size_t)(i0 + 2) * 256 + cl]);
    o[3] = f2bf(Wt[(size_t)(i0 + 3) * 256 + cl]);
    *(us4*)&Wt_s[cl * 128 + (((i0 >> 3) ^ (cl & 7)) * 8) + (i0 & 7)] = o;
  }
  __syncthreads();
  // b2[o] = sum_i K2[o][i]*bt[i] + bz[o]  (threads 0..127)
  if (t < 128) {
    float s = 0.f;
    for (int i = 0; i < 128; ++i)
      s += bf2f(K2_s[t * 128 + (((i >> 3) ^ (t & 7)) * 8) + (i & 7)]) * bt[i];
    b2[b * 256 + o0 + t] = s + bz[o0 + t];
  }
  // MFMA2: W2[o][c] = sum_i K2[o][i] * WtT[c][i], two 128-col chunks.
  #pragma unroll
  for (int cc = 0; cc < 2; ++cc) {
    f32x4 acc2[2][8] = {};
    #pragma unroll
    for (int ks = 0; ks < 4; ++ks) {
      int gc = ks * 4 + (lane >> 4);
      bf16x8 av[2], bv[8];
      #pragma unroll
      for (int fo = 0; fo < 2; ++fo) {
        int ro = w * 32 + fo * 16 + (lane & 15);
        av[fo] = *(const bf16x8*)&K2_s[ro * 128 + (gc ^ (ro & 7)) * 8];
      }
      #pragma unroll
      for (int fc = 0; fc < 8; ++fc) {
        int rc = fc * 16 + (lane & 15);
        bv[fc] = *(const bf16x8*)&Wt_s[rc * 128 + (gc ^ (rc & 7)) * 8];
      }
      #pragma unroll
      for (int fo = 0; fo < 2; ++fo)
        #pragma unroll
        for (int fc = 0; fc < 8; ++fc)
          acc2[fo][fc] = MFMA(av[fo], bv[fc], acc2[fo][fc]);
    }
    #pragma unroll
    for (int fo = 0; fo < 2; ++fo)
      #pragma unroll
      for (int q = 0; q < 4; ++q) {
        int o = o0 + w * 32 + fo * 16 + (lane >> 4) * 4 + q;
        #pragma unroll
        for (int fc = 0; fc < 8; ++fc) {
          int c = cc * 128 + fc * 16 + (lane & 15);
          W2b[((size_t)(b * 256 + o)) * 256 + c] = f2bf(acc2[fo][fc][q]);
        }
      }
    if (cc == 0) {
      __syncthreads();                       // all MFMA2 c0 reads done
      // Stage Wt chunk 1 (c in [128,256))
      #pragma unroll
      for (int it = 0; it < 16; ++it) {
        int f = it * 256 + t;
        int cl = f & 127, iq = (f >> 7) & 31;
        int i0 = iq * 4;
        us4 o;
        o[0] = f2bf(Wt[(size_t)(i0 + 0) * 256 + 128 + cl]);
        o[1] = f2bf(Wt[(size_t)(i0 + 1) * 256 + 128 + cl]);
        o[2] = f2bf(Wt[(size_t)(i0 + 2) * 256 + 128 + cl]);
        o[3] = f2bf(Wt[(size_t)(i0 + 3) * 256 + 128 + cl]);
        *(us4*)&Wt_s[cl * 128 + (((i0 >> 3) ^ (cl & 7)) * 8) + (i0 & 7)] = o;
      }
      __syncthreads();
    }
  }
}

// ---------------------------------------------------------------------------
// z = W2 @ xl + b2, xl f32 transposed+converted in LDS. grid (8, 128).
__global__ __launch_bounds__(256) void mk_z_f(
    const float* __restrict__ xl,            // [8][256][4096] f32
    const unsigned short* __restrict__ W2b,  // [8][256][256] bf16
    const float* __restrict__ b2,
    unsigned short* __restrict__ z,          // [8][256][4096] bf16
    float* __restrict__ sums) {
  __shared__ unsigned short As[256 * 64];    // 32KB [o][c-chunk]
  __shared__ unsigned short Bs[32 * 64];     // 4KB  [m][c-chunk], swizzled
  __shared__ float red[8];
  const int b = blockIdx.x, m0 = blockIdx.y * 32;
  const int t = threadIdx.x, lane = t & 63;
  const int w = t >> 6;
  const int mf = t & 7, c2 = t >> 3;
  f32x4 acc[4][2] = {};
  for (int kt = 0; kt < 4; ++kt) {
    #pragma unroll
    for (int j = 0; j < 8; ++j) {
      int slot = t + j * 256;
      int r = slot >> 3, gq = slot & 7;
      gll16(W2b + ((size_t)(b * 256 + r)) * 256 + kt * 64 + (gq ^ (r & 7)) * 8,
            As + slot * 8);
    }
    {
      const float* p = xl + ((size_t)(b * 256 + kt * 64 + 2 * c2)) * 4096 + m0 + mf * 4;
      float4 a = *(const float4*)p;
      float4 bq = *(const float4*)(p + 4096);
      const float* ap = (const float*)&a;
      const float* bp2 = (const float*)&bq;
      #pragma unroll
      for (int i = 0; i < 4; ++i) {
        int m = mf * 4 + i;
        int col32 = (((c2 >> 2) ^ (m & 7)) << 2) | (c2 & 3);
        ((unsigned*)Bs)[m * 32 + col32] = pack2(ap[i], bp2[i]);
      }
    }
    __syncthreads();
    #pragma unroll
    for (int ks = 0; ks < 2; ++ks) {
      bf16x8 av[4], bv[2];
      #pragma unroll
      for (int f = 0; f < 2; ++f) {
        int rb = f * 16 + (lane & 15);
        int gc = ks * 4 + (lane >> 4);
        bv[f] = *(const bf16x8*)&Bs[rb * 64 + (gc ^ (rb & 7)) * 8];
      }
      #pragma unroll
      for (int f = 0; f < 4; ++f) {
        int ra = w * 64 + f * 16 + (lane & 15);
        int gc = ks * 4 + (lane >> 4);
        av[f] = *(const bf16x8*)&As[ra * 64 + (gc ^ (ra & 7)) * 8];
      }
      #pragma unroll
      for (int i = 0; i < 4; ++i)
        #pragma unroll
        for (int j2 = 0; j2 < 2; ++j2)
          acc[i][j2] = MFMA(av[i], bv[j2], acc[i][j2]);
    }
    __syncthreads();
  }
  float ls = 0.f, ls2 = 0.f;
  #pragma unroll
  for (int i = 0; i < 4; ++i) {
    #pragma unroll
    for (int q = 0; q < 4; ++q) {
      int o = w * 64 + i * 16 + (lane >> 4) * 4 + q;
      float bias = b2[b * 256 + o];
      #pragma unroll
      for (int j2 = 0; j2 < 2; ++j2) {
        int m = m0 + j2 * 16 + (lane & 15);
        float v = acc[i][j2][q] + bias;
        z[((size_t)(b * 256 + o)) * 4096 + m] = f2bf(v);
        ls += v; ls2 += v * v;
      }
    }
  }
  #pragma unroll
  for (int off = 32; off > 0; off >>= 1) {
    ls  += __shfl_down(ls, off);
    ls2 += __shfl_down(ls2, off);
  }
  if ((t & 63) == 0) { red[w * 2] = ls; red[w * 2 + 1] = ls2; }
  __syncthreads();
  if (t == 0) {
    atomicAdd(&sums[b * 2 + 0], red[0] + red[2] + red[4] + red[6]);
    atomicAdd(&sums[b * 2 + 1], red[1] + red[3] + red[5] + red[7]);
  }
}

// ---------------------------------------------------------------------------
// GroupNorm(1) + affine. grid 4096.
__global__ __launch_bounds__(256) void ln_out(
    const unsigned short* __restrict__ z, const float* __restrict__ sums,
    const float* __restrict__ gamma, const float* __restrict__ beta,
    float* __restrict__ out) {
  size_t i8 = (size_t)blockIdx.x * 256 + threadIdx.x;
  int b = (int)(i8 >> 17);
  int o = (int)((i8 >> 9) & 255);
  float s = sums[b * 2], s2 = sums[b * 2 + 1];
  const float invN = 1.0f / (256.0f * 4096.0f);
  float mu = s * invN;
  float var = s2 * invN - mu * mu;
  float rs = rsqrtf(var + 1e-5f);
  float ga = gamma[o] * rs;
  float be = beta[o] - mu * rs * gamma[o];
  us8 u = *(const us8*)&z[i8 * 8];
  float4 r0, r1;
  r0.x = bf2f(u[0]) * ga + be; r0.y = bf2f(u[1]) * ga + be;
  r0.z = bf2f(u[2]) * ga + be; r0.w = bf2f(u[3]) * ga + be;
  r1.x = bf2f(u[4]) * ga + be; r1.y = bf2f(u[5]) * ga + be;
  r1.z = bf2f(u[6]) * ga + be; r1.w = bf2f(u[7]) * ga + be;
  *(float4*)&out[i8 * 8] = r0;
  *(float4*)&out[i8 * 8 + 4] = r1;
}

// ---------------------------------------------------------------------------
extern "C" void kernel_launch(void* const* d_in, const int* in_sizes, int n_in,
                              void* d_out, int out_size, void* d_ws, size_t ws_size,
                              hipStream_t stream) {
  const float* xh    = (const float*)d_in[0];
  const float* xl    = (const float*)d_in[1];
  const float* Wg    = (const float*)d_in[2];
  const float* bg    = (const float*)d_in[3];
  const float* Wt    = (const float*)d_in[4];
  const float* bt    = (const float*)d_in[5];
  const float* Wp    = (const float*)d_in[6];
  const float* bp    = (const float*)d_in[7];
  const float* Wz    = (const float*)d_in[8];
  const float* bz    = (const float*)d_in[9];
  const float* gamma = (const float*)d_in[10];
  const float* beta  = (const float*)d_in[11];
  float* out = (float*)d_out;
  float* ws = (float*)d_ws;

  // ws layout (f32 slots). zbuf [0, 4194304) overlaps ONLY dead-by-then
  // buffers (phi, gbuf, Mpart, M_bf). W2b/b2/sums live PAST zbuf's range.
  unsigned short* phi  = (unsigned short*)(ws + 0);        // [0,       524288)
  unsigned short* gbuf = (unsigned short*)(ws + 524288);   // [524288, 1048576)
  float* Mpart = ws + 1048576;                             // [1048576,2097152)
  unsigned short* M_bf = (unsigned short*)(ws + 2097152);  // [2097152,2162688)
  unsigned short* zbuf = (unsigned short*)(ws + 0);        // [0,      4194304)
  unsigned short* W2b  = (unsigned short*)(ws + 4194304);  // [4194304,4456448)
  float* b2    = ws + 4456448;                             // 2,048 f32
  float* sums  = ws + 4458496;                             // 16 f32

  hipMemsetAsync(sums, 0, 16 * sizeof(float), stream);

  proj_f2<<<dim3(8, 2, 16), 256, 0, stream>>>(xh, Wp, bp, Wg, bg, phi, gbuf);
  mpart_mfma<<<dim3(8, 8), 256, 0, stream>>>(phi, gbuf, Mpart);
  mreduce_bf<<<128, 256, 0, stream>>>(Mpart, M_bf);
  k2w2_mfma<<<dim3(8, 2), 256, 0, stream>>>(M_bf, Wz, Wt, bt, bz, W2b, b2);
  mk_z_f<<<dim3(8, 128), 256, 0, stream>>>(xl, W2b, b2, zbuf, sums);
  ln_out<<<4096, 256, 0, stream>>>(zbuf, sums, gamma, beta, out);
}